// Round 2
// baseline (456.883 us; speedup 1.0000x reference)
//
#include <hip/hip_runtime.h>

#define N_NODES 50000
#define N_EDGES 500000
#define D_NODE 64
#define D_EDGE 32
#define MSG_DIM 160
#define HID_DIM 224
#define ALPHA 0.01f

#define EPB 64          // edges per block (edge kernel)
#define NPB 64          // nodes per block (update kernel)
#define A_STRIDE 168    // 160 + 8 pad (shorts) -> 336B rows, conflict-free b128 frags
#define W_STRIDE 168
#define AH_STRIDE 232   // 224 + 8 pad

typedef unsigned short u16;
typedef short short8 __attribute__((ext_vector_type(8)));
typedef float float4v __attribute__((ext_vector_type(4)));

static __device__ __forceinline__ u16 f2bf(float f) {
    unsigned int u = __float_as_uint(f);
    u += 0x7fffu + ((u >> 16) & 1u);   // round-to-nearest-even
    return (u16)(u >> 16);
}

// generic f32 -> bf16 converter, 4 elems/thread
__global__ __launch_bounds__(256) void cvt_bf16(const float* __restrict__ in,
                                                u16* __restrict__ out, int n4) {
    int i = blockIdx.x * 256 + threadIdx.x;
    if (i < n4) {
        float4 v = reinterpret_cast<const float4*>(in)[i];
        ushort4 o;
        o.x = f2bf(v.x); o.y = f2bf(v.y); o.z = f2bf(v.z); o.w = f2bf(v.w);
        reinterpret_cast<ushort4*>(out)[i] = o;
    }
}

// ---------------- counting sort by dst ----------------
__global__ __launch_bounds__(256) void hist_kernel(const int* __restrict__ dst,
                                                   int* __restrict__ cnt) {
    int e = blockIdx.x * 256 + threadIdx.x;
    if (e < N_EDGES) atomicAdd(&cnt[dst[e]], 1);
}

// single-block exclusive scan over cnt -> cursor (50000 elems, 1024 threads)
__global__ __launch_bounds__(1024) void scan_kernel(const int* __restrict__ cnt,
                                                    int* __restrict__ cursor) {
    __shared__ int sd[1024];
    const int tid = threadIdx.x;
    const int per = (N_NODES + 1023) / 1024;            // 49
    const int lo = tid * per;
    const int hi = (lo + per < N_NODES) ? lo + per : N_NODES;
    int s = 0;
    for (int i = lo; i < hi; ++i) s += cnt[i];
    sd[tid] = s;
    __syncthreads();
    for (int off = 1; off < 1024; off <<= 1) {          // Hillis-Steele inclusive
        int v = (tid >= off) ? sd[tid - off] : 0;
        __syncthreads();
        sd[tid] += v;
        __syncthreads();
    }
    int run = sd[tid] - s;                              // exclusive prefix
    for (int i = lo; i < hi; ++i) { cursor[i] = run; run += cnt[i]; }
}

__global__ __launch_bounds__(256) void scatter_kernel(const int* __restrict__ dst,
                                                      int* __restrict__ cursor,
                                                      int* __restrict__ eid_s) {
    int e = blockIdx.x * 256 + threadIdx.x;
    if (e < N_EDGES) {
        int p = atomicAdd(&cursor[dst[e]], 1);
        eid_s[p] = e;
    }
}

// ---------------- edge message kernel (sorted order, run-aggregated atomics) ----
__global__ __launch_bounds__(256) void edge_msg_kernel(
    const u16* __restrict__ hn_bf, const float* __restrict__ h_e,
    const int* __restrict__ src, const int* __restrict__ dst,
    const int* __restrict__ eid_s,
    const u16* __restrict__ Wm_bf, const float* __restrict__ b_msg,
    float* __restrict__ m_sum)
{
    __shared__ alignas(16) u16 A_lds[EPB * A_STRIDE];   // 21504 B
    __shared__ alignas(16) u16 Wc[32 * W_STRIDE];       // 10752 B
    __shared__ float red[4][16][17];                    //  4352 B (pad 17: no 4-way wr conflict)
    __shared__ int dst_lds[EPB];                        //   256 B

    const int tid = threadIdx.x;
    const int e0 = blockIdx.x * EPB;

    // ---- stage A tile: 64 sorted edges x 160 bf16 (4 threads per edge) ----
    {
        const int e_loc = tid >> 2, j = tid & 3;
        int ee = e0 + e_loc; if (ee > N_EDGES - 1) ee = N_EDGES - 1;
        const int eo = eid_s[ee];
        const int s = src[eo], d = dst[eo];
        if (j == 0) dst_lds[e_loc] = d;
        const uint4* srow = reinterpret_cast<const uint4*>(hn_bf + (size_t)s * D_NODE);
        const uint4* drow = reinterpret_cast<const uint4*>(hn_bf + (size_t)d * D_NODE);
        uint4* Arow = reinterpret_cast<uint4*>(&A_lds[e_loc * A_STRIDE]);
        Arow[j * 2]     = srow[j * 2];        // bf16 [0,64): h_n[src]
        Arow[j * 2 + 1] = srow[j * 2 + 1];
        Arow[8 + j * 2]     = drow[j * 2];    // bf16 [64,128): h_n[dst]
        Arow[8 + j * 2 + 1] = drow[j * 2 + 1];
        const float4* he = reinterpret_cast<const float4*>(h_e + (size_t)eo * D_EDGE);
        float4 p = he[j * 2], q = he[j * 2 + 1];
        ushort4 lo, hi;
        lo.x = f2bf(p.x); lo.y = f2bf(p.y); lo.z = f2bf(p.z); lo.w = f2bf(p.w);
        hi.x = f2bf(q.x); hi.y = f2bf(q.y); hi.z = f2bf(q.z); hi.w = f2bf(q.w);
        ushort4* Aus = reinterpret_cast<ushort4*>(Arow);
        Aus[32 + j * 2]     = lo;             // bf16 [128,160): h_e
        Aus[32 + j * 2 + 1] = hi;
    }
    __syncthreads();

    const int wave = tid >> 6, lane = tid & 63;
    const int qd = lane >> 4, l15 = lane & 15;

    // A fragments for this wave's 16 edges, all 5 K-steps (kept in regs)
    short8 a_frag[5];
#pragma unroll
    for (int ks = 0; ks < 5; ++ks)
        a_frag[ks] = *reinterpret_cast<const short8*>(
            &A_lds[(wave * 16 + l15) * A_STRIDE + ks * 32 + qd * 8]);

    for (int c = 0; c < 5; ++c) {            // 5 chunks of 32 output features
        if (c) __syncthreads();
        for (int f = tid; f < 32 * 20; f += 256) {   // stage W rows [c*32, c*32+32)
            int row = f / 20, col = f % 20;
            reinterpret_cast<uint4*>(&Wc[row * W_STRIDE])[col] =
                reinterpret_cast<const uint4*>(Wm_bf)[(c * 32 + row) * 20 + col];
        }
        __syncthreads();

#pragma unroll
        for (int it2 = 0; it2 < 2; ++it2) {
            const int fbase = c * 32 + it2 * 16;
            float4v acc = {0.f, 0.f, 0.f, 0.f};
#pragma unroll
            for (int ks = 0; ks < 5; ++ks) {
                short8 b = *reinterpret_cast<const short8*>(
                    &Wc[(it2 * 16 + l15) * W_STRIDE + ks * 32 + qd * 8]);
                acc = __builtin_amdgcn_mfma_f32_16x16x32_bf16(a_frag[ks], b, acc, 0, 0, 0);
            }
            const float bias = b_msg[fbase + l15];
            // write bias+leaky'd values to per-wave LDS tile (C layout: row=qd*4+r, col=l15)
#pragma unroll
            for (int r = 0; r < 4; ++r) {
                const int row = qd * 4 + r;
                float v = acc[r] + bias;
                v = v > 0.f ? v : ALPHA * v;
                const bool ok = (e0 + wave * 16 + row) < N_EDGES;
                red[wave][row][l15] = ok ? v : 0.f;
            }
            __syncthreads();   // uniform control flow; makes the LDS transpose visible
            // lanes 0..15: each owns one feature column; walk sorted-dst runs
            if (lane < 16) {
                const int f = fbase + lane;
                float sum = red[wave][0][lane];
                int cur = dst_lds[wave * 16];
                for (int i = 1; i < 16; ++i) {          // branch uniform across 16 lanes
                    const int dn = dst_lds[wave * 16 + i];
                    const float v = red[wave][i][lane];
                    if (dn == cur) { sum += v; }
                    else {
                        atomicAdd(&m_sum[(size_t)cur * MSG_DIM + f], sum);
                        cur = dn; sum = v;
                    }
                }
                atomicAdd(&m_sum[(size_t)cur * MSG_DIM + f], sum);
            }
        }
    }
}

// ---------------- node update kernel ----------------
// out[n][i] = leaky( sum_k [m_sum|h_n][n][k] * W_hid[i][k] + b_hid[i] )
__global__ __launch_bounds__(256) void update_kernel(
    const float* __restrict__ m_sum, const u16* __restrict__ hn_bf,
    const u16* __restrict__ Wh_bf, const float* __restrict__ b_hid,
    float* __restrict__ out)
{
    __shared__ alignas(16) u16 A_lds[NPB * AH_STRIDE];
    const int tid = threadIdx.x;
    const int n0 = blockIdx.x * NPB;

    {   // stage 64 nodes x 224 bf16 (4 threads per node)
        const int n_loc = tid >> 2, j = tid & 3;
        int n = n0 + n_loc; if (n > N_NODES - 1) n = N_NODES - 1;
        const float4* mrow = reinterpret_cast<const float4*>(m_sum + (size_t)n * MSG_DIM);
        uint4* Au = reinterpret_cast<uint4*>(&A_lds[n_loc * AH_STRIDE]);
        ushort4* Aus = reinterpret_cast<ushort4*>(Au);
#pragma unroll
        for (int p = 0; p < 5; ++p) {        // bf16 [0,160): m_sum (fp32->bf16)
            float4 x = mrow[j * 10 + p * 2], y = mrow[j * 10 + p * 2 + 1];
            ushort4 lo, hi;
            lo.x = f2bf(x.x); lo.y = f2bf(x.y); lo.z = f2bf(x.z); lo.w = f2bf(x.w);
            hi.x = f2bf(y.x); hi.y = f2bf(y.y); hi.z = f2bf(y.z); hi.w = f2bf(y.w);
            Aus[(j * 5 + p) * 2]     = lo;
            Aus[(j * 5 + p) * 2 + 1] = hi;
        }
        const uint4* hrow = reinterpret_cast<const uint4*>(hn_bf + (size_t)n * D_NODE);
        Au[20 + j * 2]     = hrow[j * 2];    // bf16 [160,224): h_n
        Au[20 + j * 2 + 1] = hrow[j * 2 + 1];
    }
    __syncthreads();

    const int wave = tid >> 6, lane = tid & 63;
    const int qd = lane >> 4, l15 = lane & 15;

    short8 a_frag[7];
#pragma unroll
    for (int ks = 0; ks < 7; ++ks)
        a_frag[ks] = *reinterpret_cast<const short8*>(
            &A_lds[(wave * 16 + l15) * AH_STRIDE + ks * 32 + qd * 8]);

    for (int it = 0; it < 14; ++it) {
        const int i = it * 16 + l15;
        float4v acc = {0.f, 0.f, 0.f, 0.f};
#pragma unroll
        for (int ks = 0; ks < 7; ++ks) {
            short8 b = *reinterpret_cast<const short8*>(
                Wh_bf + (size_t)i * HID_DIM + ks * 32 + qd * 8);
            acc = __builtin_amdgcn_mfma_f32_16x16x32_bf16(a_frag[ks], b, acc, 0, 0, 0);
        }
        const float bias = b_hid[i];
#pragma unroll
        for (int r = 0; r < 4; ++r) {
            const int n = n0 + wave * 16 + qd * 4 + r;
            if (n < N_NODES) {
                float v = acc[r] + bias;
                v = v > 0.f ? v : ALPHA * v;
                out[(size_t)n * HID_DIM + i] = v;
            }
        }
    }
}

extern "C" void kernel_launch(void* const* d_in, const int* in_sizes, int n_in,
                              void* d_out, int out_size, void* d_ws, size_t ws_size,
                              hipStream_t stream)
{
    const float* h_n   = (const float*)d_in[0];
    const float* h_e   = (const float*)d_in[1];
    const int*   src   = (const int*)d_in[2];
    const int*   dst   = (const int*)d_in[3];
    const float* W_msg = (const float*)d_in[4];
    const float* b_msg = (const float*)d_in[5];
    const float* W_hid = (const float*)d_in[6];
    const float* b_hid = (const float*)d_in[7];
    float* out = (float*)d_out;

    char* ws = (char*)d_ws;
    float* m_sum  = (float*)ws;                      // 50000*160*4 = 32,000,000 B
    u16*   hn_bf  = (u16*)(ws + 32000000);           // 50000*64*2  =  6,400,000 B
    u16*   Wm_bf  = (u16*)(ws + 38400000);           // 160*160*2   =     51,200 B
    u16*   Wh_bf  = (u16*)(ws + 38451200);           // 224*224*2   =    100,352 B
    int*   cnt    = (int*)(ws + 38551552);           // 50000*4     =    200,000 B
    int*   cursor = (int*)(ws + 38751552);           // 50000*4     =    200,000 B
    int*   eid_s  = (int*)(ws + 38951552);           // 500000*4    =  2,000,000 B
                                                     // total ~40.95 MB

    hipMemsetAsync(m_sum, 0, (size_t)N_NODES * MSG_DIM * sizeof(float), stream);
    hipMemsetAsync(cnt, 0, (size_t)N_NODES * sizeof(int), stream);

    cvt_bf16<<<(N_NODES * D_NODE / 4 + 255) / 256, 256, 0, stream>>>(h_n, hn_bf, N_NODES * D_NODE / 4);
    cvt_bf16<<<(MSG_DIM * MSG_DIM / 4 + 255) / 256, 256, 0, stream>>>(W_msg, Wm_bf, MSG_DIM * MSG_DIM / 4);
    cvt_bf16<<<(HID_DIM * HID_DIM / 4 + 255) / 256, 256, 0, stream>>>(W_hid, Wh_bf, HID_DIM * HID_DIM / 4);

    hist_kernel<<<(N_EDGES + 255) / 256, 256, 0, stream>>>(dst, cnt);
    scan_kernel<<<1, 1024, 0, stream>>>(cnt, cursor);
    scatter_kernel<<<(N_EDGES + 255) / 256, 256, 0, stream>>>(dst, cursor, eid_s);

    edge_msg_kernel<<<(N_EDGES + EPB - 1) / EPB, 256, 0, stream>>>(
        hn_bf, h_e, src, dst, eid_s, Wm_bf, b_msg, m_sum);
    update_kernel<<<(N_NODES + NPB - 1) / NPB, 256, 0, stream>>>(
        m_sum, hn_bf, Wh_bf, b_hid, out);
}

// Round 3
// 410.436 us; speedup vs baseline: 1.1132x; 1.1132x over previous
//
#include <hip/hip_runtime.h>

#define N_NODES 50000
#define N_EDGES 500000
#define D_NODE 64
#define D_EDGE 32
#define MSG_DIM 160
#define HID_DIM 224
#define ALPHA 0.01f

#define EPB 64          // edges per block (edge kernel)
#define NPB 64          // nodes per block (update kernel)
#define A_STRIDE 168    // 160 + 8 pad (shorts) -> conflict-free b128 frag reads
#define AH_STRIDE 232   // 224 + 8 pad
#define NPART 196       // ceil(50000/256) scan partials

typedef unsigned short u16;
typedef short short8 __attribute__((ext_vector_type(8)));
typedef float float4v __attribute__((ext_vector_type(4)));

static __device__ __forceinline__ u16 f2bf(float f) {
    unsigned int u = __float_as_uint(f);
    u += 0x7fffu + ((u >> 16) & 1u);   // round-to-nearest-even
    return (u16)(u >> 16);
}

// generic f32 -> bf16 converter, 4 elems/thread
__global__ __launch_bounds__(256) void cvt_bf16(const float* __restrict__ in,
                                                u16* __restrict__ out, int n4) {
    int i = blockIdx.x * 256 + threadIdx.x;
    if (i < n4) {
        float4 v = reinterpret_cast<const float4*>(in)[i];
        ushort4 o;
        o.x = f2bf(v.x); o.y = f2bf(v.y); o.z = f2bf(v.z); o.w = f2bf(v.w);
        reinterpret_cast<ushort4*>(out)[i] = o;
    }
}

// ---------------- counting sort by dst (hist -> hierarchical scan -> scatter) ----
__global__ __launch_bounds__(256) void hist_kernel(const int* __restrict__ dst,
                                                   int* __restrict__ cnt) {
    int e = blockIdx.x * 256 + threadIdx.x;
    if (e < N_EDGES) atomicAdd(&cnt[dst[e]], 1);
}

__global__ __launch_bounds__(256) void partial_kernel(const int* __restrict__ cnt,
                                                      int* __restrict__ partial) {
    __shared__ int sd[256];
    const int tid = threadIdx.x;
    int i = blockIdx.x * 256 + tid;
    sd[tid] = (i < N_NODES) ? cnt[i] : 0;
    __syncthreads();
    for (int off = 128; off > 0; off >>= 1) {
        if (tid < off) sd[tid] += sd[tid + off];
        __syncthreads();
    }
    if (tid == 0) partial[blockIdx.x] = sd[0];
}

__global__ __launch_bounds__(256) void offs_kernel(int* __restrict__ partial) {
    __shared__ int sd[256];
    const int t = threadIdx.x;
    int v = (t < NPART) ? partial[t] : 0;
    sd[t] = v;
    __syncthreads();
    for (int off = 1; off < 256; off <<= 1) {
        int u = (t >= off) ? sd[t - off] : 0;
        __syncthreads();
        sd[t] += u;
        __syncthreads();
    }
    if (t < NPART) partial[t] = sd[t] - v;   // exclusive
}

__global__ __launch_bounds__(256) void cursor_kernel(const int* __restrict__ cnt,
                                                     const int* __restrict__ partial,
                                                     int* __restrict__ cursor) {
    __shared__ int sd[256];
    const int tid = threadIdx.x;
    int i = blockIdx.x * 256 + tid;
    int v = (i < N_NODES) ? cnt[i] : 0;
    sd[tid] = v;
    __syncthreads();
    for (int off = 1; off < 256; off <<= 1) {
        int u = (tid >= off) ? sd[tid - off] : 0;
        __syncthreads();
        sd[tid] += u;
        __syncthreads();
    }
    if (i < N_NODES) cursor[i] = partial[blockIdx.x] + sd[tid] - v;  // exclusive
}

__global__ __launch_bounds__(256) void scatter_kernel(const int* __restrict__ src,
                                                      const int* __restrict__ dst,
                                                      int* __restrict__ cursor,
                                                      int* __restrict__ eid_s,
                                                      int* __restrict__ src_s,
                                                      int* __restrict__ dst_s) {
    int e = blockIdx.x * 256 + threadIdx.x;
    if (e < N_EDGES) {
        int d = dst[e];
        int p = atomicAdd(&cursor[d], 1);
        eid_s[p] = e;
        src_s[p] = src[e];
        dst_s[p] = d;
    }
}

// ---------------- edge message kernel ----------------
// Transposed MFMA: C[f][e] = leaky( W_msg[f][:] . X[e][:] + b[f] )
// lane l15 owns edge (tile_base + l15); 4 features qd*4+r.
// Segmented shuffle-scan over sorted dsts, one atomic per (run, feature).
__global__ __launch_bounds__(256) void edge_msg_kernel(
    const u16* __restrict__ hn_bf, const float* __restrict__ h_e,
    const int* __restrict__ src_s, const int* __restrict__ dst_s,
    const int* __restrict__ eid_s,
    const u16* __restrict__ Wm_bf, const float* __restrict__ b_msg,
    float* __restrict__ m_sum)
{
    __shared__ alignas(16) u16 A_lds[EPB * A_STRIDE];   // 21504 B
    __shared__ int dst_lds[EPB];

    const int tid = threadIdx.x;
    const int e0 = blockIdx.x * EPB;

    // ---- stage X tile: 64 sorted edges x 160 bf16 (4 threads per edge) ----
    {
        const int e_loc = tid >> 2, j = tid & 3;
        int ee = e0 + e_loc; if (ee > N_EDGES - 1) ee = N_EDGES - 1;
        const int s = src_s[ee], d = dst_s[ee], eo = eid_s[ee];
        if (j == 0) dst_lds[e_loc] = d;
        const uint4* srow = reinterpret_cast<const uint4*>(hn_bf + (size_t)s * D_NODE);
        const uint4* drow = reinterpret_cast<const uint4*>(hn_bf + (size_t)d * D_NODE);
        uint4* Arow = reinterpret_cast<uint4*>(&A_lds[e_loc * A_STRIDE]);
        Arow[j * 2]     = srow[j * 2];        // bf16 [0,64): h_n[src]
        Arow[j * 2 + 1] = srow[j * 2 + 1];
        Arow[8 + j * 2]     = drow[j * 2];    // bf16 [64,128): h_n[dst]
        Arow[8 + j * 2 + 1] = drow[j * 2 + 1];
        const float4* he = reinterpret_cast<const float4*>(h_e + (size_t)eo * D_EDGE);
        float4 p = he[j * 2], q = he[j * 2 + 1];
        ushort4 lo, hi;
        lo.x = f2bf(p.x); lo.y = f2bf(p.y); lo.z = f2bf(p.z); lo.w = f2bf(p.w);
        hi.x = f2bf(q.x); hi.y = f2bf(q.y); hi.z = f2bf(q.z); hi.w = f2bf(q.w);
        ushort4* Aus = reinterpret_cast<ushort4*>(Arow);
        Aus[32 + j * 2]     = lo;             // bf16 [128,160): h_e
        Aus[32 + j * 2 + 1] = hi;
    }
    __syncthreads();

    const int wave = tid >> 6, lane = tid & 63;
    const int qd = lane >> 4, l15 = lane & 15;

    // X fragments (B operand): lane holds edge l15, k = qd*8+j
    short8 x_frag[5];
#pragma unroll
    for (int ks = 0; ks < 5; ++ks)
        x_frag[ks] = *reinterpret_cast<const short8*>(
            &A_lds[(wave * 16 + l15) * A_STRIDE + ks * 32 + qd * 8]);

    const int my_dst = dst_lds[wave * 16 + l15];
    const bool ok = (e0 + wave * 16 + l15) < N_EDGES;

    // run structure is chunk-invariant: precompute scan predicates + seg_last
    const int nxt = __shfl(my_dst, (lane + 1) & 63);
    const bool seg_last = (l15 == 15) || (nxt != my_dst);
    bool pr[4];
#pragma unroll
    for (int s = 1, i = 0; s < 16; s <<= 1, ++i) {
        int pd = __shfl(my_dst, (lane - s) & 63);
        pr[i] = (l15 >= s) && (pd == my_dst);
    }

    for (int c = 0; c < 10; ++c) {           // 10 chunks of 16 output features
        const int fbase = c * 16;
        // W fragments (A operand): lane holds feature row fbase+l15, direct from L2
        float4v acc = {0.f, 0.f, 0.f, 0.f};
#pragma unroll
        for (int ks = 0; ks < 5; ++ks) {
            short8 w = *reinterpret_cast<const short8*>(
                Wm_bf + (size_t)(fbase + l15) * MSG_DIM + ks * 32 + qd * 8);
            acc = __builtin_amdgcn_mfma_f32_16x16x32_bf16(w, x_frag[ks], acc, 0, 0, 0);
        }
        const float4 bias = *reinterpret_cast<const float4*>(b_msg + fbase + qd * 4);
        float v0 = acc[0] + bias.x, v1 = acc[1] + bias.y,
              v2 = acc[2] + bias.z, v3 = acc[3] + bias.w;
        v0 = v0 > 0.f ? v0 : ALPHA * v0;  v1 = v1 > 0.f ? v1 : ALPHA * v1;
        v2 = v2 > 0.f ? v2 : ALPHA * v2;  v3 = v3 > 0.f ? v3 : ALPHA * v3;
        if (!ok) { v0 = v1 = v2 = v3 = 0.f; }

        // segmented inclusive scan along l15 (runs of equal dst)
#pragma unroll
        for (int s = 1, i = 0; s < 16; s <<= 1, ++i) {
            const int sl = (lane - s) & 63;
            float t0 = __shfl(v0, sl), t1 = __shfl(v1, sl),
                  t2 = __shfl(v2, sl), t3 = __shfl(v3, sl);
            if (pr[i]) { v0 += t0; v1 += t1; v2 += t2; v3 += t3; }
        }
        if (seg_last) {
            float* row = &m_sum[(size_t)my_dst * MSG_DIM + fbase + qd * 4];
            atomicAdd(row + 0, v0);
            atomicAdd(row + 1, v1);
            atomicAdd(row + 2, v2);
            atomicAdd(row + 3, v3);
        }
    }
}

// ---------------- node update kernel ----------------
// out[n][i] = leaky( sum_k [m_sum|h_n][n][k] * W_hid[i][k] + b_hid[i] )
__global__ __launch_bounds__(256) void update_kernel(
    const float* __restrict__ m_sum, const u16* __restrict__ hn_bf,
    const u16* __restrict__ Wh_bf, const float* __restrict__ b_hid,
    float* __restrict__ out)
{
    __shared__ alignas(16) u16 A_lds[NPB * AH_STRIDE];
    const int tid = threadIdx.x;
    const int n0 = blockIdx.x * NPB;

    {   // stage 64 nodes x 224 bf16 (4 threads per node)
        const int n_loc = tid >> 2, j = tid & 3;
        int n = n0 + n_loc; if (n > N_NODES - 1) n = N_NODES - 1;
        const float4* mrow = reinterpret_cast<const float4*>(m_sum + (size_t)n * MSG_DIM);
        uint4* Au = reinterpret_cast<uint4*>(&A_lds[n_loc * AH_STRIDE]);
        ushort4* Aus = reinterpret_cast<ushort4*>(Au);
#pragma unroll
        for (int p = 0; p < 5; ++p) {        // bf16 [0,160): m_sum (fp32->bf16)
            float4 x = mrow[j * 10 + p * 2], y = mrow[j * 10 + p * 2 + 1];
            ushort4 lo, hi;
            lo.x = f2bf(x.x); lo.y = f2bf(x.y); lo.z = f2bf(x.z); lo.w = f2bf(x.w);
            hi.x = f2bf(y.x); hi.y = f2bf(y.y); hi.z = f2bf(y.z); hi.w = f2bf(y.w);
            Aus[(j * 5 + p) * 2]     = lo;
            Aus[(j * 5 + p) * 2 + 1] = hi;
        }
        const uint4* hrow = reinterpret_cast<const uint4*>(hn_bf + (size_t)n * D_NODE);
        Au[20 + j * 2]     = hrow[j * 2];    // bf16 [160,224): h_n
        Au[20 + j * 2 + 1] = hrow[j * 2 + 1];
    }
    __syncthreads();

    const int wave = tid >> 6, lane = tid & 63;
    const int qd = lane >> 4, l15 = lane & 15;

    short8 a_frag[7];
#pragma unroll
    for (int ks = 0; ks < 7; ++ks)
        a_frag[ks] = *reinterpret_cast<const short8*>(
            &A_lds[(wave * 16 + l15) * AH_STRIDE + ks * 32 + qd * 8]);

    for (int it = 0; it < 14; ++it) {
        const int i = it * 16 + l15;
        float4v acc = {0.f, 0.f, 0.f, 0.f};
#pragma unroll
        for (int ks = 0; ks < 7; ++ks) {
            short8 b = *reinterpret_cast<const short8*>(
                Wh_bf + (size_t)i * HID_DIM + ks * 32 + qd * 8);
            acc = __builtin_amdgcn_mfma_f32_16x16x32_bf16(a_frag[ks], b, acc, 0, 0, 0);
        }
        const float bias = b_hid[i];
#pragma unroll
        for (int r = 0; r < 4; ++r) {
            const int n = n0 + wave * 16 + qd * 4 + r;
            if (n < N_NODES) {
                float v = acc[r] + bias;
                v = v > 0.f ? v : ALPHA * v;
                out[(size_t)n * HID_DIM + i] = v;
            }
        }
    }
}

extern "C" void kernel_launch(void* const* d_in, const int* in_sizes, int n_in,
                              void* d_out, int out_size, void* d_ws, size_t ws_size,
                              hipStream_t stream)
{
    const float* h_n   = (const float*)d_in[0];
    const float* h_e   = (const float*)d_in[1];
    const int*   src   = (const int*)d_in[2];
    const int*   dst   = (const int*)d_in[3];
    const float* W_msg = (const float*)d_in[4];
    const float* b_msg = (const float*)d_in[5];
    const float* W_hid = (const float*)d_in[6];
    const float* b_hid = (const float*)d_in[7];
    float* out = (float*)d_out;

    char* ws = (char*)d_ws;
    float* m_sum   = (float*)ws;                     // 32,000,000 B
    u16*   hn_bf   = (u16*)(ws + 32000000);          //  6,400,000 B
    u16*   Wm_bf   = (u16*)(ws + 38400000);          //     51,200 B
    u16*   Wh_bf   = (u16*)(ws + 38451200);          //    100,352 B
    int*   cnt     = (int*)(ws + 38551552);          //    200,000 B
    int*   cursor  = (int*)(ws + 38751552);          //    200,000 B
    int*   eid_s   = (int*)(ws + 38951552);          //  2,000,000 B
    int*   src_s   = (int*)(ws + 40951552);          //  2,000,000 B
    int*   dst_s   = (int*)(ws + 42951552);          //  2,000,000 B
    int*   partial = (int*)(ws + 44951552);          //        784 B   (~45 MB total)

    hipMemsetAsync(m_sum, 0, (size_t)N_NODES * MSG_DIM * sizeof(float), stream);
    hipMemsetAsync(cnt, 0, (size_t)N_NODES * sizeof(int), stream);

    cvt_bf16<<<(N_NODES * D_NODE / 4 + 255) / 256, 256, 0, stream>>>(h_n, hn_bf, N_NODES * D_NODE / 4);
    cvt_bf16<<<(MSG_DIM * MSG_DIM / 4 + 255) / 256, 256, 0, stream>>>(W_msg, Wm_bf, MSG_DIM * MSG_DIM / 4);
    cvt_bf16<<<(HID_DIM * HID_DIM / 4 + 255) / 256, 256, 0, stream>>>(W_hid, Wh_bf, HID_DIM * HID_DIM / 4);

    hist_kernel<<<(N_EDGES + 255) / 256, 256, 0, stream>>>(dst, cnt);
    partial_kernel<<<NPART, 256, 0, stream>>>(cnt, partial);
    offs_kernel<<<1, 256, 0, stream>>>(partial);
    cursor_kernel<<<NPART, 256, 0, stream>>>(cnt, partial, cursor);
    scatter_kernel<<<(N_EDGES + 255) / 256, 256, 0, stream>>>(src, dst, cursor, eid_s, src_s, dst_s);

    edge_msg_kernel<<<(N_EDGES + EPB - 1) / EPB, 256, 0, stream>>>(
        hn_bf, h_e, src_s, dst_s, eid_s, Wm_bf, b_msg, m_sum);
    update_kernel<<<(N_NODES + NPB - 1) / NPB, 256, 0, stream>>>(
        m_sum, hn_bf, Wh_bf, b_hid, out);
}